// Round 1
// baseline (1396.736 us; speedup 1.0000x reference)
//
#include <hip/hip_runtime.h>

#define N_CAPS 219024   // 117*117*16
#define J_CAPS 8

typedef __attribute__((ext_vector_type(8))) __bf16 bf16x8;
typedef __attribute__((ext_vector_type(4))) float  f32x4;
typedef __attribute__((ext_vector_type(8))) short  short8;

__device__ __forceinline__ unsigned short f2bf(float f) {
    unsigned int u = __float_as_uint(f);
    u = (u + 0x7FFFu + ((u >> 16) & 1u)) >> 16;   // RNE
    return (unsigned short)u;
}

// ---------------- conv1: [2,250,250,3] x [9,9,3,256] s1 VALID -> relu -> bf16 [2,242,242,256]
__global__ __launch_bounds__(256) void conv1_kernel(
    const float* __restrict__ in, const float* __restrict__ w,
    const float* __restrict__ bias, unsigned short* __restrict__ out)
{
    const int oc  = threadIdx.x;
    const int ox0 = blockIdx.x * 16;
    const int oy  = blockIdx.y;
    const int b   = blockIdx.z;

    __shared__ float lin[9][24][3];
    for (int idx = threadIdx.x; idx < 9 * 24 * 3; idx += 256) {
        int r   = idx / (24 * 3);
        int rem = idx - r * (24 * 3);
        int col = rem / 3;
        int c   = rem - col * 3;
        int iy  = oy + r;
        int ix  = ox0 + col;
        float v = 0.f;
        if (ix < 250) v = in[((b * 250 + iy) * 250 + ix) * 3 + c];
        lin[r][col][c] = v;
    }
    __syncthreads();

    float acc[16];
#pragma unroll
    for (int t = 0; t < 16; ++t) acc[t] = 0.f;

    for (int ky = 0; ky < 9; ++ky) {
#pragma unroll
        for (int ic = 0; ic < 3; ++ic) {
            float xv[24];
#pragma unroll
            for (int c2 = 0; c2 < 24; ++c2) xv[c2] = lin[ky][c2][ic];
#pragma unroll
            for (int kx = 0; kx < 9; ++kx) {
                float wv = w[((ky * 9 + kx) * 3 + ic) * 256 + oc];
#pragma unroll
                for (int t = 0; t < 16; ++t)
                    acc[t] += xv[kx + t] * wv;
            }
        }
    }

    float bv = bias[oc];
#pragma unroll
    for (int t = 0; t < 16; ++t) {
        int ox = ox0 + t;
        if (ox < 242) {
            float v = acc[t] + bv;
            out[((b * 242 + oy) * 242 + ox) * 256 + oc] = f2bf(v > 0.f ? v : 0.f);
        }
    }
}

// ---------------- w2 [9,9,256,128] fp32 -> w2t [81,128,256] bf16 (p, oc, ic)
__global__ __launch_bounds__(256) void w2_convert_kernel(
    const float* __restrict__ w, unsigned short* __restrict__ wt)
{
    int idx = blockIdx.x * 256 + threadIdx.x;     // output-ordered: ((p*128+oc)*256+ic)
    if (idx >= 81 * 128 * 256) return;
    int ic = idx & 255;
    int t  = idx >> 8;
    int oc = t & 127;
    int p  = t >> 7;
    wt[idx] = f2bf(w[(p * 256 + ic) * 128 + oc]);
}

// ---------------- conv2 implicit GEMM v2, bf16 MFMA 16x16x32
// Restructure vs v1:
//  * wave tile 64M x 64N (was 64x32): each A ds_read_b128 feeds 4 MFMAs (was 2),
//    halving LDS-pipe demand; B stays global (L2-resident w2t), total B traffic
//    unchanged (~2.3 GB) since M-per-wave is unchanged at 64.
//  * block = 2 waves (128 thr), block tile 64M x 128N, LDS 34.5 KB -> 4 blocks/CU
//  * split-K x3 over ky (grid 468 -> 1404 blocks): 4 independent resident blocks
//    per CU hide stage-barrier drains; fp32 partials summed in squash_u.
//  * s_setprio(1) around each 16-MFMA burst (independent blocks per CU -> T5).
__global__ __launch_bounds__(128, 2) void conv2_mfma_kernel(
    const unsigned short* __restrict__ x1bf,   // [2,242,242,256] bf16
    const unsigned short* __restrict__ w2t,    // [81,128,256] bf16
    float* __restrict__ part)                  // [3][2,117,117,128] fp32 partials
{
    const int bx   = blockIdx.x;               // 6: oxt = bx&1, kys = bx>>1
    const int oxt  = bx & 1;
    const int kys  = bx >> 1;                  // 0..2 (ky group of 3)
    const int oy   = blockIdx.y;
    const int b    = blockIdx.z;
    const int tid  = threadIdx.x;
    const int wave = tid >> 6;                 // 0..1
    const int lane = tid & 63;
    const int li   = lane & 15;
    const int quad = lane >> 4;
    const int wn   = wave * 64;                // wave's oc base (64 oc per wave)
    const int ox0  = oxt * 64;
    const int ky0  = kys * 3;

    // A: [col 0..135) x [128 ic half], per col 16 chunks of 8 bf16, XOR-swizzled
    __shared__ __align__(16) unsigned short As[135 * 128];   // 34,560 B

    f32x4 acc[4][4];
#pragma unroll
    for (int mt = 0; mt < 4; ++mt)
#pragma unroll
        for (int nt = 0; nt < 4; ++nt)
            acc[mt][nt] = (f32x4){0.f, 0.f, 0.f, 0.f};

    size_t bofs[4];
#pragma unroll
    for (int nt = 0; nt < 4; ++nt)
        bofs[nt] = (size_t)(wn + nt * 16 + li) * 256 + quad * 8;

    for (int kk = 0; kk < 3; ++kk) {
        const int ky = ky0 + kk;
        const int iy = 2 * oy + ky;                          // <= 240, in-bounds
        const unsigned short* xrow =
            x1bf + ((size_t)(b * 242 + iy) * 242 + 2 * ox0) * 256;

        for (int hq = 0; hq < 2; ++hq) {                     // ic half
            __syncthreads();                                 // prior As readers done
            // stage A half: 135 cols x 16 chunks of 16 B, swizzled source
            for (int it = 0; it < 17; ++it) {
                int ct = it * 128 + tid;
                if (ct < 135 * 16) {
                    int col = ct >> 4;
                    int cc  = ct & 15;
                    int src = cc ^ ((col >> 1) & 7);
                    *(short8*)&As[ct * 8] =
                        *(const short8*)&xrow[col * 256 + hq * 128 + src * 8];
                }
            }
            __syncthreads();

            for (int kx = 0; kx < 9; ++kx) {
                const unsigned short* wp =
                    w2t + ((size_t)(ky * 9 + kx) << 15) + hq * 128;
                const int sw = (li + (kx >> 1)) & 7;
                const unsigned short* abase = As + (2 * li + kx) * 128;
#pragma unroll
                for (int kc = 0; kc < 4; ++kc) {             // 32-ic MFMA chunks
                    bf16x8 bfr[4];
#pragma unroll
                    for (int nt = 0; nt < 4; ++nt)
                        bfr[nt] = *(const bf16x8*)&wp[bofs[nt] + kc * 32];
                    const int chs = ((kc << 2) + quad) ^ sw;
                    __builtin_amdgcn_s_setprio(1);
#pragma unroll
                    for (int mt = 0; mt < 4; ++mt) {
                        bf16x8 a = *(const bf16x8*)&abase[mt * 4096 + chs * 8];
#pragma unroll
                        for (int nt = 0; nt < 4; ++nt)
                            acc[mt][nt] = __builtin_amdgcn_mfma_f32_16x16x32_bf16(
                                a, bfr[nt], acc[mt][nt], 0, 0, 0);
                    }
                    __builtin_amdgcn_s_setprio(0);
                }
            }
        }
    }

    // epilogue: C/D layout col(N)=lane&15, row(M)=quad*4+reg; raw partial, no bias
    float* pp = part + (size_t)kys * (2ull * 117 * 117 * 128)
              + (size_t)(b * 117 + oy) * 117 * 128;
#pragma unroll
    for (int mt = 0; mt < 4; ++mt) {
#pragma unroll
        for (int r = 0; r < 4; ++r) {
            const int ox = ox0 + mt * 16 + quad * 4 + r;
            if (ox < 117) {
                float* op = pp + (size_t)ox * 128 + li;
                op[wn]      = acc[mt][0][r];
                op[wn + 16] = acc[mt][1][r];
                op[wn + 32] = acc[mt][2][r];
                op[wn + 48] = acc[mt][3][r];
            }
        }
    }
}

// ---------------- sum 3 K-split partials + bias, squash over groups of 8 -> u
__global__ __launch_bounds__(256) void squash_u_kernel(
    const float* __restrict__ part, const float* __restrict__ bias,
    float* __restrict__ u, int n_groups)
{
    int g = blockIdx.x * 256 + threadIdx.x;
    if (g >= n_groups) return;
    const size_t PSZ = 2ull * 117 * 117 * 128;   // floats per partial
    const float4* p0 = (const float4*)(part + (size_t)g * 8);
    const float4* p1 = (const float4*)(part + PSZ + (size_t)g * 8);
    const float4* p2 = (const float4*)(part + 2 * PSZ + (size_t)g * 8);
    const float4* bp = (const float4*)(bias + (g & 15) * 8);
    float4 a0 = p0[0], c0 = p0[1];
    float4 a1 = p1[0], c1 = p1[1];
    float4 a2 = p2[0], c2 = p2[1];
    float4 ba = bp[0], bc = bp[1];
    float x[8];
    x[0] = a0.x + a1.x + a2.x + ba.x;
    x[1] = a0.y + a1.y + a2.y + ba.y;
    x[2] = a0.z + a1.z + a2.z + ba.z;
    x[3] = a0.w + a1.w + a2.w + ba.w;
    x[4] = c0.x + c1.x + c2.x + bc.x;
    x[5] = c0.y + c1.y + c2.y + bc.y;
    x[6] = c0.z + c1.z + c2.z + bc.z;
    x[7] = c0.w + c1.w + c2.w + bc.w;
    float sq = 0.f;
#pragma unroll
    for (int j = 0; j < 8; ++j) sq += x[j] * x[j];
    float scale = (sq / (1.f + sq)) * rsqrtf(sq + 1e-7f);
    float4* d = (float4*)(u + (size_t)g * 8);
    d[0] = make_float4(x[0] * scale, x[1] * scale, x[2] * scale, x[3] * scale);
    d[1] = make_float4(x[4] * scale, x[5] * scale, x[6] * scale, x[7] * scale);
}

// ---------------- u_hat[b,j,i,o] = sum_d W[j,i,o,d] * u[b,i,d]
__global__ __launch_bounds__(256) void uhat_kernel(
    const float* __restrict__ W, const float* __restrict__ u,
    float* __restrict__ uhat)
{
    int idx = blockIdx.x * 256 + threadIdx.x;   // idx = j*N + i
    if (idx >= J_CAPS * N_CAPS) return;
    int j = idx / N_CAPS;
    int i = idx - j * N_CAPS;

    const float4* wp = (const float4*)(W + (size_t)idx * 64);
    const float4* u0 = (const float4*)(u + (size_t)i * 8);
    const float4* u1 = (const float4*)(u + ((size_t)N_CAPS + i) * 8);
    float4 u0a = u0[0], u0b = u0[1];
    float4 u1a = u1[0], u1b = u1[1];

    float o0[8], o1[8];
#pragma unroll
    for (int o = 0; o < 8; ++o) {
        float4 wa = wp[2 * o], wb = wp[2 * o + 1];
        o0[o] = wa.x * u0a.x + wa.y * u0a.y + wa.z * u0a.z + wa.w * u0a.w
              + wb.x * u0b.x + wb.y * u0b.y + wb.z * u0b.z + wb.w * u0b.w;
        o1[o] = wa.x * u1a.x + wa.y * u1a.y + wa.z * u1a.z + wa.w * u1a.w
              + wb.x * u1b.x + wb.y * u1b.y + wb.z * u1b.z + wb.w * u1b.w;
    }
    float4* d0 = (float4*)(uhat + ((size_t)(0 * J_CAPS + j) * N_CAPS + i) * 8);
    float4* d1 = (float4*)(uhat + ((size_t)(1 * J_CAPS + j) * N_CAPS + i) * 8);
    d0[0] = make_float4(o0[0], o0[1], o0[2], o0[3]);
    d0[1] = make_float4(o0[4], o0[5], o0[6], o0[7]);
    d1[0] = make_float4(o1[0], o1[1], o1[2], o1[3]);
    d1[1] = make_float4(o1[4], o1[5], o1[6], o1[7]);
}

// ---------------- fused routing iteration (MODE 0/1/2)
template <int MODE>
__global__ __launch_bounds__(256) void routing_kernel(
    const float* __restrict__ uhat, const float* __restrict__ vprev,
    const float* __restrict__ b_in, float* __restrict__ b_out,
    float* __restrict__ s)
{
    const int bb = blockIdx.y;
    __shared__ float vsh[64];
    __shared__ float ssh[64];
    if (threadIdx.x < 64) {
        ssh[threadIdx.x] = 0.f;
        vsh[threadIdx.x] = (MODE > 0) ? vprev[bb * 64 + threadIdx.x] : 0.f;
    }
    __syncthreads();

    float acc[64];
#pragma unroll
    for (int k = 0; k < 64; ++k) acc[k] = 0.f;

    const float* ub = uhat + (size_t)bb * J_CAPS * (size_t)N_CAPS * 8;
    for (int i = blockIdx.x * 256 + threadIdx.x; i < N_CAPS; i += gridDim.x * 256) {
        float uh[64];
#pragma unroll
        for (int j = 0; j < 8; ++j) {
            const float* p = ub + ((size_t)j * N_CAPS + i) * 8;
            float4 x0 = *(const float4*)p;
            float4 x1 = *(const float4*)(p + 4);
            uh[j * 8 + 0] = x0.x; uh[j * 8 + 1] = x0.y;
            uh[j * 8 + 2] = x0.z; uh[j * 8 + 3] = x0.w;
            uh[j * 8 + 4] = x1.x; uh[j * 8 + 5] = x1.y;
            uh[j * 8 + 6] = x1.z; uh[j * 8 + 7] = x1.w;
        }
        float c[8];
        if (MODE == 0) {
#pragma unroll
            for (int j = 0; j < 8; ++j) c[j] = 0.125f;
        } else {
            float bj[8];
#pragma unroll
            for (int j = 0; j < 8; ++j) {
                float d = 0.f;
#pragma unroll
                for (int o = 0; o < 8; ++o) d += vsh[j * 8 + o] * uh[j * 8 + o];
                bj[j] = d;
            }
            if (MODE == 2) {
#pragma unroll
                for (int j = 0; j < 8; ++j)
                    bj[j] += b_in[((size_t)bb * 8 + j) * N_CAPS + i];
            } else {
#pragma unroll
                for (int j = 0; j < 8; ++j)
                    b_out[((size_t)bb * 8 + j) * N_CAPS + i] = bj[j];
            }
            float m = bj[0];
#pragma unroll
            for (int j = 1; j < 8; ++j) m = fmaxf(m, bj[j]);
            float se = 0.f;
#pragma unroll
            for (int j = 0; j < 8; ++j) { c[j] = __expf(bj[j] - m); se += c[j]; }
            float inv = 1.f / se;
#pragma unroll
            for (int j = 0; j < 8; ++j) c[j] *= inv;
        }
#pragma unroll
        for (int k = 0; k < 64; ++k) acc[k] += c[k >> 3] * uh[k];
    }

#pragma unroll
    for (int k = 0; k < 64; ++k) {
        float v = acc[k];
        for (int off = 32; off > 0; off >>= 1)
            v += __shfl_down(v, off, 64);
        if ((threadIdx.x & 63) == 0) atomicAdd(&ssh[k], v);
    }
    __syncthreads();
    if (threadIdx.x < 64) atomicAdd(&s[bb * 64 + threadIdx.x], ssh[threadIdx.x]);
}

// ---------------- squash of s -> v
__global__ void squash_v_kernel(const float* __restrict__ s, float* __restrict__ v)
{
    int t = threadIdx.x;
    if (t >= 16) return;
    const float4* p = (const float4*)(s + t * 8);
    float4 a = p[0], c = p[1];
    float sq = a.x * a.x + a.y * a.y + a.z * a.z + a.w * a.w
             + c.x * c.x + c.y * c.y + c.z * c.z + c.w * c.w;
    float scale = (sq / (1.f + sq)) * rsqrtf(sq + 1e-7f);
    float4* d = (float4*)(v + t * 8);
    d[0] = make_float4(a.x * scale, a.y * scale, a.z * scale, a.w * scale);
    d[1] = make_float4(c.x * scale, c.y * scale, c.z * scale, c.w * scale);
}

__global__ void zero_kernel(float* p, int n)
{
    int i = blockIdx.x * 256 + threadIdx.x;
    if (i < n) p[i] = 0.f;
}

extern "C" void kernel_launch(void* const* d_in, const int* in_sizes, int n_in,
                              void* d_out, int out_size, void* d_ws, size_t ws_size,
                              hipStream_t stream)
{
    const float* in = (const float*)d_in[0];
    const float* w1 = (const float*)d_in[1];
    const float* b1 = (const float*)d_in[2];
    const float* w2 = (const float*)d_in[3];
    const float* b2 = (const float*)d_in[4];
    const float* Wc = (const float*)d_in[5];
    float* out = (float*)d_out;
    char* wsb  = (char*)d_ws;

    // workspace layout (bytes):
    //  [0, 112,140,288):  uhat fp32 [2,8,219024,8]; earlier in the stream this
    //                     region is aliased by:
    //                       x1bf bf16 [2,242,242,256]  = [0, 59,969,536)
    //                       pcpart fp32 [3][2,117,117,128] = [59,969,536, 102,022,144)
    //                     (both dead before uhat is written)
    //  [112,140,288):     pc/u fp32 (14,017,536 B)
    //  [126,157,824):     blog fp32 (14,017,536 B)
    //  [140,175,360):     w2t bf16 (5,308,416 B)
    //  [145,483,776):     sbuf (512 B); [145,484,288): vbuf (512 B)
    float*          uhat   = (float*)wsb;
    unsigned short* x1bf   = (unsigned short*)wsb;
    float*          pcpart = (float*)(wsb + 59969536);
    float*          pc     = (float*)(wsb + 112140288);
    float*          blog   = (float*)(wsb + 126157824);
    unsigned short* w2t    = (unsigned short*)(wsb + 140175360);
    float*          sbuf   = (float*)(wsb + 145483776);
    float*          vbuf   = (float*)(wsb + 145484288);

    w2_convert_kernel<<<(81 * 128 * 256 + 255) / 256, 256, 0, stream>>>(w2, w2t);
    conv1_kernel<<<dim3(16, 242, 2), 256, 0, stream>>>(in, w1, b1, x1bf);
    conv2_mfma_kernel<<<dim3(6, 117, 2), 128, 0, stream>>>(x1bf, w2t, pcpart);
    squash_u_kernel<<<(2 * N_CAPS + 255) / 256, 256, 0, stream>>>(pcpart, b2, pc, 2 * N_CAPS);
    uhat_kernel<<<(J_CAPS * N_CAPS + 255) / 256, 256, 0, stream>>>(Wc, pc, uhat);

    zero_kernel<<<1, 128, 0, stream>>>(sbuf, 128);
    routing_kernel<0><<<dim3(256, 2), 256, 0, stream>>>(uhat, nullptr, nullptr, nullptr, sbuf);
    squash_v_kernel<<<1, 64, 0, stream>>>(sbuf, vbuf);

    zero_kernel<<<1, 128, 0, stream>>>(sbuf, 128);
    routing_kernel<1><<<dim3(256, 2), 256, 0, stream>>>(uhat, vbuf, nullptr, blog, sbuf);
    squash_v_kernel<<<1, 64, 0, stream>>>(sbuf, vbuf);

    zero_kernel<<<1, 128, 0, stream>>>(sbuf, 128);
    routing_kernel<2><<<dim3(256, 2), 256, 0, stream>>>(uhat, vbuf, blog, nullptr, sbuf);
    squash_v_kernel<<<1, 64, 0, stream>>>(sbuf, out);
}

// Round 2
// 1271.315 us; speedup vs baseline: 1.0987x; 1.0987x over previous
//
#include <hip/hip_runtime.h>

#define N_CAPS 219024   // 117*117*16
#define J_CAPS 8

typedef __attribute__((ext_vector_type(8))) __bf16 bf16x8;
typedef __attribute__((ext_vector_type(4))) float  f32x4;
typedef __attribute__((ext_vector_type(8))) short  short8;

typedef const __attribute__((address_space(1))) unsigned int gld_t;
typedef __attribute__((address_space(3))) unsigned int lds_t;

__device__ __forceinline__ unsigned short f2bf(float f) {
    unsigned int u = __float_as_uint(f);
    u = (u + 0x7FFFu + ((u >> 16) & 1u)) >> 16;   // RNE
    return (unsigned short)u;
}

// ---------------- conv1: [2,250,250,3] x [9,9,3,256] s1 VALID -> relu -> bf16 [2,242,242,256]
__global__ __launch_bounds__(256) void conv1_kernel(
    const float* __restrict__ in, const float* __restrict__ w,
    const float* __restrict__ bias, unsigned short* __restrict__ out)
{
    const int oc  = threadIdx.x;
    const int ox0 = blockIdx.x * 16;
    const int oy  = blockIdx.y;
    const int b   = blockIdx.z;

    __shared__ float lin[9][24][3];
    for (int idx = threadIdx.x; idx < 9 * 24 * 3; idx += 256) {
        int r   = idx / (24 * 3);
        int rem = idx - r * (24 * 3);
        int col = rem / 3;
        int c   = rem - col * 3;
        int iy  = oy + r;
        int ix  = ox0 + col;
        float v = 0.f;
        if (ix < 250) v = in[((b * 250 + iy) * 250 + ix) * 3 + c];
        lin[r][col][c] = v;
    }
    __syncthreads();

    float acc[16];
#pragma unroll
    for (int t = 0; t < 16; ++t) acc[t] = 0.f;

    for (int ky = 0; ky < 9; ++ky) {
#pragma unroll
        for (int ic = 0; ic < 3; ++ic) {
            float xv[24];
#pragma unroll
            for (int c2 = 0; c2 < 24; ++c2) xv[c2] = lin[ky][c2][ic];
#pragma unroll
            for (int kx = 0; kx < 9; ++kx) {
                float wv = w[((ky * 9 + kx) * 3 + ic) * 256 + oc];
#pragma unroll
                for (int t = 0; t < 16; ++t)
                    acc[t] += xv[kx + t] * wv;
            }
        }
    }

    float bv = bias[oc];
#pragma unroll
    for (int t = 0; t < 16; ++t) {
        int ox = ox0 + t;
        if (ox < 242) {
            float v = acc[t] + bv;
            out[((b * 242 + oy) * 242 + ox) * 256 + oc] = f2bf(v > 0.f ? v : 0.f);
        }
    }
}

// ---------------- w2 [9,9,256,128] fp32 -> w2t [81,128,256] bf16 (p, oc, ic)
__global__ __launch_bounds__(256) void w2_convert_kernel(
    const float* __restrict__ w, unsigned short* __restrict__ wt)
{
    int idx = blockIdx.x * 256 + threadIdx.x;     // output-ordered: ((p*128+oc)*256+ic)
    if (idx >= 81 * 128 * 256) return;
    int ic = idx & 255;
    int t  = idx >> 8;
    int oc = t & 127;
    int p  = t >> 7;
    wt[idx] = f2bf(w[(p * 256 + ic) * 128 + oc]);
}

// ---------------- conv2 implicit GEMM v3, bf16 MFMA 16x16x32
// v1 geometry (256 thr / 4 waves, wave = 64M x 32N, 4 blocks/CU) + T3 pipeline:
//  * A staged at quarter-ic granularity (135 cols x 64 ic = 17.3 KB), DOUBLE-
//    buffered (34.6 KB total, same residency as v1).
//  * staging via global_load_lds width=16, source pre-swizzled, LDS linear.
//  * STAGE(p+1) issued BEFORE compute(p); one __syncthreads per phase -> the
//    vmcnt(0) drain lands after a full compute phase, hiding stage latency
//    (v1 exposed it: stage -> sync -> compute).
__global__ __launch_bounds__(256, 4) void conv2_mfma_kernel(
    const unsigned short* __restrict__ x1bf,   // [2,242,242,256] bf16
    const unsigned short* __restrict__ w2t,    // [81,128,256] bf16
    const float* __restrict__ bias,
    float* __restrict__ out)                   // [2,117,117,128] fp32
{
    const int bx   = blockIdx.x;               // 0,1: ox tile of 64
    const int oy   = blockIdx.y;
    const int b    = blockIdx.z;
    const int tid  = threadIdx.x;
    const int wave = tid >> 6;
    const int lane = tid & 63;
    const int li   = lane & 15;
    const int quad = lane >> 4;
    const int wn   = wave * 32;
    const int ox0  = bx * 64;

    // per buffer: 135 cols x 8 chunks (64 ic) of 8 bf16; chunk XOR-swizzled
    __shared__ __align__(16) unsigned short As[2][135 * 64];   // 2 x 17,280 B

    f32x4 acc[4][2];
#pragma unroll
    for (int mt = 0; mt < 4; ++mt) {
        acc[mt][0] = (f32x4){0.f, 0.f, 0.f, 0.f};
        acc[mt][1] = (f32x4){0.f, 0.f, 0.f, 0.f};
    }

    const int n0 = wn + li;          // nt=0 oc
    const int n1 = wn + 16 + li;     // nt=1 oc
    const size_t bofs0 = (size_t)n0 * 256 + quad * 8;
    const size_t bofs1 = (size_t)n1 * 256 + quad * 8;

    const unsigned short* xbase =
        x1bf + ((size_t)(b * 242 + 2 * oy) * 242 + 2 * ox0) * 256;

    // stage phase p (p = ky*4 + q) into As[p&1]
    auto stage = [&](int p) {
        const int ky = p >> 2;
        const int q  = p & 3;
        const unsigned short* xr = xbase + (size_t)ky * (242 * 256) + q * 64;
        unsigned short* db = &As[p & 1][0];
#pragma unroll
        for (int it = 0; it < 5; ++it) {
            int ct = it * 256 + tid;                 // ct = col*8 + cc, 1080 total
            if (ct < 135 * 8) {
                int col = ct >> 3;
                int cc  = ct & 7;
                int src = cc ^ ((col >> 1) & 7);
                // LDS dest: wave-uniform base + lane*16 (linear), matches ct*16
                __builtin_amdgcn_global_load_lds(
                    (gld_t*)(xr + (size_t)col * 256 + src * 8),
                    (lds_t*)(db + (size_t)(it * 256 + wave * 64) * 8),
                    16, 0, 0);
            }
        }
    };

    stage(0);
    __syncthreads();

    for (int p = 0; p < 36; ++p) {
        if (p < 35) stage(p + 1);                    // prefetch next quarter

        const int ky = p >> 2;
        const int q  = p & 3;
        const unsigned short* asb = As[p & 1];

        for (int kx = 0; kx < 9; ++kx) {
            const unsigned short* wp =
                w2t + ((size_t)(ky * 9 + kx) << 15) + q * 64;
            const int sw = (li + (kx >> 1)) & 7;
            const int colb = 2 * li + kx;
#pragma unroll
            for (int kc = 0; kc < 2; ++kc) {         // two 32-ic MFMA chunks
                bf16x8 b0 = *(const bf16x8*)&wp[bofs0 + kc * 32];
                bf16x8 b1 = *(const bf16x8*)&wp[bofs1 + kc * 32];
                const int c4 = ((kc << 2) + quad) ^ sw;
#pragma unroll
                for (int mt = 0; mt < 4; ++mt) {
                    bf16x8 a = *(const bf16x8*)&asb[(size_t)(mt * 32 + colb) * 64 + c4 * 8];
                    acc[mt][0] = __builtin_amdgcn_mfma_f32_16x16x32_bf16(a, b0, acc[mt][0], 0, 0, 0);
                    acc[mt][1] = __builtin_amdgcn_mfma_f32_16x16x32_bf16(a, b1, acc[mt][1], 0, 0, 0);
                }
            }
        }
        __syncthreads();                             // drains stage(p+1) loads too
    }

    // epilogue: C/D layout col(N)=lane&15, row(M)=quad*4+reg
    const float bv0 = bias[n0];
    const float bv1 = bias[n1];
#pragma unroll
    for (int mt = 0; mt < 4; ++mt) {
#pragma unroll
        for (int r = 0; r < 4; ++r) {
            const int m  = mt * 16 + quad * 4 + r;
            const int ox = ox0 + m;
            if (ox < 117) {
                float* op = &out[((size_t)(b * 117 + oy) * 117 + ox) * 128];
                op[n0] = acc[mt][0][r] + bv0;
                op[n1] = acc[mt][1][r] + bv1;
            }
        }
    }
}

// ---------------- squash over groups of 8 (in-place)
__global__ __launch_bounds__(256) void squash_u_kernel(float* data, int n_groups)
{
    int i = blockIdx.x * 256 + threadIdx.x;
    if (i >= n_groups) return;
    float4* p = (float4*)(data + (size_t)i * 8);
    float4 a = p[0], c = p[1];
    float sq = a.x * a.x + a.y * a.y + a.z * a.z + a.w * a.w
             + c.x * c.x + c.y * c.y + c.z * c.z + c.w * c.w;
    float scale = (sq / (1.f + sq)) * rsqrtf(sq + 1e-7f);
    p[0] = make_float4(a.x * scale, a.y * scale, a.z * scale, a.w * scale);
    p[1] = make_float4(c.x * scale, c.y * scale, c.z * scale, c.w * scale);
}

// ---------------- u_hat[b,j,i,o] = sum_d W[j,i,o,d] * u[b,i,d]
__global__ __launch_bounds__(256) void uhat_kernel(
    const float* __restrict__ W, const float* __restrict__ u,
    float* __restrict__ uhat)
{
    int idx = blockIdx.x * 256 + threadIdx.x;   // idx = j*N + i
    if (idx >= J_CAPS * N_CAPS) return;
    int j = idx / N_CAPS;
    int i = idx - j * N_CAPS;

    const float4* wp = (const float4*)(W + (size_t)idx * 64);
    const float4* u0 = (const float4*)(u + (size_t)i * 8);
    const float4* u1 = (const float4*)(u + ((size_t)N_CAPS + i) * 8);
    float4 u0a = u0[0], u0b = u0[1];
    float4 u1a = u1[0], u1b = u1[1];

    float o0[8], o1[8];
#pragma unroll
    for (int o = 0; o < 8; ++o) {
        float4 wa = wp[2 * o], wb = wp[2 * o + 1];
        o0[o] = wa.x * u0a.x + wa.y * u0a.y + wa.z * u0a.z + wa.w * u0a.w
              + wb.x * u0b.x + wb.y * u0b.y + wb.z * u0b.z + wb.w * u0b.w;
        o1[o] = wa.x * u1a.x + wa.y * u1a.y + wa.z * u1a.z + wa.w * u1a.w
              + wb.x * u1b.x + wb.y * u1b.y + wb.z * u1b.z + wb.w * u1b.w;
    }
    float4* d0 = (float4*)(uhat + ((size_t)(0 * J_CAPS + j) * N_CAPS + i) * 8);
    float4* d1 = (float4*)(uhat + ((size_t)(1 * J_CAPS + j) * N_CAPS + i) * 8);
    d0[0] = make_float4(o0[0], o0[1], o0[2], o0[3]);
    d0[1] = make_float4(o0[4], o0[5], o0[6], o0[7]);
    d1[0] = make_float4(o1[0], o1[1], o1[2], o1[3]);
    d1[1] = make_float4(o1[4], o1[5], o1[6], o1[7]);
}

// ---------------- fused routing iteration (MODE 0/1/2)
template <int MODE>
__global__ __launch_bounds__(256) void routing_kernel(
    const float* __restrict__ uhat, const float* __restrict__ vprev,
    const float* __restrict__ b_in, float* __restrict__ b_out,
    float* __restrict__ s)
{
    const int bb = blockIdx.y;
    __shared__ float vsh[64];
    __shared__ float ssh[64];
    if (threadIdx.x < 64) {
        ssh[threadIdx.x] = 0.f;
        vsh[threadIdx.x] = (MODE > 0) ? vprev[bb * 64 + threadIdx.x] : 0.f;
    }
    __syncthreads();

    float acc[64];
#pragma unroll
    for (int k = 0; k < 64; ++k) acc[k] = 0.f;

    const float* ub = uhat + (size_t)bb * J_CAPS * (size_t)N_CAPS * 8;
    for (int i = blockIdx.x * 256 + threadIdx.x; i < N_CAPS; i += gridDim.x * 256) {
        float uh[64];
#pragma unroll
        for (int j = 0; j < 8; ++j) {
            const float* p = ub + ((size_t)j * N_CAPS + i) * 8;
            float4 x0 = *(const float4*)p;
            float4 x1 = *(const float4*)(p + 4);
            uh[j * 8 + 0] = x0.x; uh[j * 8 + 1] = x0.y;
            uh[j * 8 + 2] = x0.z; uh[j * 8 + 3] = x0.w;
            uh[j * 8 + 4] = x1.x; uh[j * 8 + 5] = x1.y;
            uh[j * 8 + 6] = x1.z; uh[j * 8 + 7] = x1.w;
        }
        float c[8];
        if (MODE == 0) {
#pragma unroll
            for (int j = 0; j < 8; ++j) c[j] = 0.125f;
        } else {
            float bj[8];
#pragma unroll
            for (int j = 0; j < 8; ++j) {
                float d = 0.f;
#pragma unroll
                for (int o = 0; o < 8; ++o) d += vsh[j * 8 + o] * uh[j * 8 + o];
                bj[j] = d;
            }
            if (MODE == 2) {
#pragma unroll
                for (int j = 0; j < 8; ++j)
                    bj[j] += b_in[((size_t)bb * 8 + j) * N_CAPS + i];
            } else {
#pragma unroll
                for (int j = 0; j < 8; ++j)
                    b_out[((size_t)bb * 8 + j) * N_CAPS + i] = bj[j];
            }
            float m = bj[0];
#pragma unroll
            for (int j = 1; j < 8; ++j) m = fmaxf(m, bj[j]);
            float se = 0.f;
#pragma unroll
            for (int j = 0; j < 8; ++j) { c[j] = __expf(bj[j] - m); se += c[j]; }
            float inv = 1.f / se;
#pragma unroll
            for (int j = 0; j < 8; ++j) c[j] *= inv;
        }
#pragma unroll
        for (int k = 0; k < 64; ++k) acc[k] += c[k >> 3] * uh[k];
    }

#pragma unroll
    for (int k = 0; k < 64; ++k) {
        float v = acc[k];
        for (int off = 32; off > 0; off >>= 1)
            v += __shfl_down(v, off, 64);
        if ((threadIdx.x & 63) == 0) atomicAdd(&ssh[k], v);
    }
    __syncthreads();
    if (threadIdx.x < 64) atomicAdd(&s[bb * 64 + threadIdx.x], ssh[threadIdx.x]);
}

// ---------------- squash of s -> v
__global__ void squash_v_kernel(const float* __restrict__ s, float* __restrict__ v)
{
    int t = threadIdx.x;
    if (t >= 16) return;
    const float4* p = (const float4*)(s + t * 8);
    float4 a = p[0], c = p[1];
    float sq = a.x * a.x + a.y * a.y + a.z * a.z + a.w * a.w
             + c.x * c.x + c.y * c.y + c.z * c.z + c.w * c.w;
    float scale = (sq / (1.f + sq)) * rsqrtf(sq + 1e-7f);
    float4* d = (float4*)(v + t * 8);
    d[0] = make_float4(a.x * scale, a.y * scale, a.z * scale, a.w * scale);
    d[1] = make_float4(c.x * scale, c.y * scale, c.z * scale, c.w * scale);
}

__global__ void zero_kernel(float* p, int n)
{
    int i = blockIdx.x * 256 + threadIdx.x;
    if (i < n) p[i] = 0.f;
}

extern "C" void kernel_launch(void* const* d_in, const int* in_sizes, int n_in,
                              void* d_out, int out_size, void* d_ws, size_t ws_size,
                              hipStream_t stream)
{
    const float* in = (const float*)d_in[0];
    const float* w1 = (const float*)d_in[1];
    const float* b1 = (const float*)d_in[2];
    const float* w2 = (const float*)d_in[3];
    const float* b2 = (const float*)d_in[4];
    const float* Wc = (const float*)d_in[5];
    float* out = (float*)d_out;
    char* wsb  = (char*)d_ws;

    // workspace layout (bytes):
    //  [0, 112,140,288):  uhat fp32 [2,8,219024,8]; aliased by x1bf bf16 (dead before uhat)
    //  [112,140,288):     pc fp32  (14,017,536 B)
    //  [126,157,824):     blog fp32 (14,017,536 B)
    //  [140,175,360):     w2t bf16 (5,308,416 B)
    //  [145,483,776):     sbuf (512 B); [145,484,288): vbuf (512 B)
    float*          uhat = (float*)wsb;
    unsigned short* x1bf = (unsigned short*)wsb;
    float*          pc   = (float*)(wsb + 112140288);
    float*          blog = (float*)(wsb + 126157824);
    unsigned short* w2t  = (unsigned short*)(wsb + 140175360);
    float*          sbuf = (float*)(wsb + 145483776);
    float*          vbuf = (float*)(wsb + 145484288);

    w2_convert_kernel<<<(81 * 128 * 256 + 255) / 256, 256, 0, stream>>>(w2, w2t);
    conv1_kernel<<<dim3(16, 242, 2), 256, 0, stream>>>(in, w1, b1, x1bf);
    conv2_mfma_kernel<<<dim3(2, 117, 2), 256, 0, stream>>>(x1bf, w2t, b2, pc);
    squash_u_kernel<<<(2 * N_CAPS + 255) / 256, 256, 0, stream>>>(pc, 2 * N_CAPS);
    uhat_kernel<<<(J_CAPS * N_CAPS + 255) / 256, 256, 0, stream>>>(Wc, pc, uhat);

    zero_kernel<<<1, 128, 0, stream>>>(sbuf, 128);
    routing_kernel<0><<<dim3(256, 2), 256, 0, stream>>>(uhat, nullptr, nullptr, nullptr, sbuf);
    squash_v_kernel<<<1, 64, 0, stream>>>(sbuf, vbuf);

    zero_kernel<<<1, 128, 0, stream>>>(sbuf, 128);
    routing_kernel<1><<<dim3(256, 2), 256, 0, stream>>>(uhat, vbuf, nullptr, blog, sbuf);
    squash_v_kernel<<<1, 64, 0, stream>>>(sbuf, vbuf);

    zero_kernel<<<1, 128, 0, stream>>>(sbuf, 128);
    routing_kernel<2><<<dim3(256, 2), 256, 0, stream>>>(uhat, vbuf, blog, nullptr, sbuf);
    squash_v_kernel<<<1, 64, 0, stream>>>(sbuf, out);
}

// Round 3
// 1258.091 us; speedup vs baseline: 1.1102x; 1.0105x over previous
//
#include <hip/hip_runtime.h>

#define N_CAPS 219024   // 117*117*16
#define J_CAPS 8

typedef __attribute__((ext_vector_type(8))) __bf16 bf16x8;
typedef __attribute__((ext_vector_type(4))) float  f32x4;
typedef __attribute__((ext_vector_type(8))) short  short8;

typedef const __attribute__((address_space(1))) unsigned int gld_t;
typedef __attribute__((address_space(3))) unsigned int lds_t;

__device__ __forceinline__ unsigned short f2bf(float f) {
    unsigned int u = __float_as_uint(f);
    u = (u + 0x7FFFu + ((u >> 16) & 1u)) >> 16;   // RNE
    return (unsigned short)u;
}

// ---------------- conv1: [2,250,250,3] x [9,9,3,256] s1 VALID -> relu -> bf16 [2,242,242,256]
__global__ __launch_bounds__(256) void conv1_kernel(
    const float* __restrict__ in, const float* __restrict__ w,
    const float* __restrict__ bias, unsigned short* __restrict__ out)
{
    const int oc  = threadIdx.x;
    const int ox0 = blockIdx.x * 16;
    const int oy  = blockIdx.y;
    const int b   = blockIdx.z;

    // transposed: [ky][ic][col] so per-(ky,ic) row reads are contiguous (b128-able)
    __shared__ float lin[9][3][24];
    for (int idx = threadIdx.x; idx < 9 * 24 * 3; idx += 256) {
        int r   = idx / (24 * 3);
        int rem = idx - r * (24 * 3);
        int col = rem / 3;
        int c   = rem - col * 3;
        int iy  = oy + r;
        int ix  = ox0 + col;
        float v = 0.f;
        if (ix < 250) v = in[((b * 250 + iy) * 250 + ix) * 3 + c];
        lin[r][c][col] = v;
    }
    __syncthreads();

    float acc[16];
#pragma unroll
    for (int t = 0; t < 16; ++t) acc[t] = 0.f;

    for (int ky = 0; ky < 9; ++ky) {
#pragma unroll
        for (int ic = 0; ic < 3; ++ic) {
            float xv[24];
#pragma unroll
            for (int c2 = 0; c2 < 24; ++c2) xv[c2] = lin[ky][ic][c2];
#pragma unroll
            for (int kx = 0; kx < 9; ++kx) {
                float wv = w[((ky * 9 + kx) * 3 + ic) * 256 + oc];
#pragma unroll
                for (int t = 0; t < 16; ++t)
                    acc[t] += xv[kx + t] * wv;
            }
        }
    }

    float bv = bias[oc];
#pragma unroll
    for (int t = 0; t < 16; ++t) {
        int ox = ox0 + t;
        if (ox < 242) {
            float v = acc[t] + bv;
            out[((b * 242 + oy) * 242 + ox) * 256 + oc] = f2bf(v > 0.f ? v : 0.f);
        }
    }
}

// ---------------- w2 [9,9,256,128] fp32 -> w2t [81,128,256] bf16 (p, oc, ic)
__global__ __launch_bounds__(256) void w2_convert_kernel(
    const float* __restrict__ w, unsigned short* __restrict__ wt)
{
    int idx = blockIdx.x * 256 + threadIdx.x;     // output-ordered: ((p*128+oc)*256+ic)
    if (idx >= 81 * 128 * 256) return;
    int ic = idx & 255;
    int t  = idx >> 8;
    int oc = t & 127;
    int p  = t >> 7;
    wt[idx] = f2bf(w[(p * 256 + ic) * 128 + oc]);
}

// ---------------- conv2 implicit GEMM v4, bf16 MFMA 16x16x32
// v3 pipelined structure (256 thr / 4 waves, wave 64Mx32N, A quarter-ic double
// buffer, global_load_lds staging, STAGE(p+1)-before-compute(p)) plus:
//  * split-K x3 over ky: grid 468 -> 1404 blocks (5.5/CU, 4 resident), kys is
//    the slowest grid dim so co-scheduled blocks share one 1.73MB w2t slice.
//  * group-padded LDS: each 8-col group (1024 B) padded to 1056 B (+8 banks),
//    separating the 3-bit-XOR's residual 2-way collision pairs (colb dist 8/24
//    -> bank offset 8/24). Wave writes exactly one group -> gld_lds dest stays
//    wave-uniform base + lane*16.
//  * fp32 partials (no bias); summed+biased+squashed in squash_u.
__global__ __launch_bounds__(256, 4) void conv2_mfma_kernel(
    const unsigned short* __restrict__ x1bf,   // [2,242,242,256] bf16
    const unsigned short* __restrict__ w2t,    // [81,128,256] bf16
    float* __restrict__ part)                  // [3][2,117,117,128] fp32
{
    const int bx   = blockIdx.x;               // 0,1: ox tile of 64
    const int oy   = blockIdx.y;
    const int bz   = blockIdx.z;               // b + 2*kys
    const int b    = bz & 1;
    const int kys  = bz >> 1;                  // 0..2
    const int tid  = threadIdx.x;
    const int wave = tid >> 6;
    const int lane = tid & 63;
    const int li   = lane & 15;
    const int quad = lane >> 4;
    const int wn   = wave * 32;
    const int ox0  = bx * 64;
    const int ky0  = kys * 3;

    // per buffer: 17 groups x 1056 B (8 cols x 8 chunks of 16 B, +32 B pad)
    __shared__ __align__(16) unsigned short As[2][8976];   // 2 x 17,952 B

    f32x4 acc[4][2];
#pragma unroll
    for (int mt = 0; mt < 4; ++mt) {
        acc[mt][0] = (f32x4){0.f, 0.f, 0.f, 0.f};
        acc[mt][1] = (f32x4){0.f, 0.f, 0.f, 0.f};
    }

    const int n0 = wn + li;
    const int n1 = wn + 16 + li;
    const size_t bofs0 = (size_t)n0 * 256 + quad * 8;
    const size_t bofs1 = (size_t)n1 * 256 + quad * 8;

    const unsigned short* xbase =
        x1bf + ((size_t)(b * 242 + 2 * oy) * 242 + 2 * ox0) * 256;

    // stage phase p (p = kk*4 + q, ky = ky0+kk) into As[p&1]
    auto stage = [&](int p) {
        const int ky = ky0 + (p >> 2);
        const int q  = p & 3;
        const unsigned short* xr = xbase + (size_t)ky * (242 * 256) + q * 64;
        unsigned short* db = &As[p & 1][0];
#pragma unroll
        for (int it = 0; it < 5; ++it) {
            int ct = it * 256 + tid;                 // ct = col*8 + cc, 1080 total
            if (ct < 135 * 8) {
                int col = ct >> 3;
                int cc  = ct & 7;
                int src = cc ^ ((col >> 1) & 7);
                // dest: group-padded; wave writes one 1024B group -> uniform base
                __builtin_amdgcn_global_load_lds(
                    (gld_t*)(xr + (size_t)col * 256 + src * 8),
                    (lds_t*)(db + (size_t)(ct >> 6) * 528 + (size_t)(ct & 63) * 8),
                    16, 0, 0);
            }
        }
    };

    stage(0);
    __syncthreads();

    for (int p = 0; p < 12; ++p) {
        if (p < 11) stage(p + 1);                    // prefetch next quarter

        const int ky = ky0 + (p >> 2);
        const int q  = p & 3;
        const unsigned short* asb = As[p & 1];

        for (int kx = 0; kx < 9; ++kx) {
            const unsigned short* wp =
                w2t + ((size_t)(ky * 9 + kx) << 15) + q * 64;
            const int colb0 = 2 * li + kx;
            const int base0 = (colb0 >> 3) * 528 + (colb0 & 7) * 64;
            const int sw    = (colb0 >> 1) & 7;
#pragma unroll
            for (int kc = 0; kc < 2; ++kc) {         // two 32-ic MFMA chunks
                bf16x8 b0 = *(const bf16x8*)&wp[bofs0 + kc * 32];
                bf16x8 b1 = *(const bf16x8*)&wp[bofs1 + kc * 32];
                const int c4 = ((kc << 2) + quad) ^ sw;
#pragma unroll
                for (int mt = 0; mt < 4; ++mt) {
                    bf16x8 a = *(const bf16x8*)&asb[base0 + mt * 2112 + c4 * 8];
                    acc[mt][0] = __builtin_amdgcn_mfma_f32_16x16x32_bf16(a, b0, acc[mt][0], 0, 0, 0);
                    acc[mt][1] = __builtin_amdgcn_mfma_f32_16x16x32_bf16(a, b1, acc[mt][1], 0, 0, 0);
                }
            }
        }
        __syncthreads();                             // drains stage(p+1) loads too
    }

    // epilogue: C/D layout col(N)=lane&15, row(M)=quad*4+reg; raw partial
    float* pp = part + (size_t)kys * (2ull * 117 * 117 * 128)
              + (size_t)(b * 117 + oy) * 117 * 128;
#pragma unroll
    for (int mt = 0; mt < 4; ++mt) {
#pragma unroll
        for (int r = 0; r < 4; ++r) {
            const int m  = mt * 16 + quad * 4 + r;
            const int ox = ox0 + m;
            if (ox < 117) {
                float* op = pp + (size_t)ox * 128;
                op[n0] = acc[mt][0][r];
                op[n1] = acc[mt][1][r];
            }
        }
    }
}

// ---------------- sum 3 K-split partials + bias, squash over groups of 8 -> u
__global__ __launch_bounds__(256) void squash_u_kernel(
    const float* __restrict__ part, const float* __restrict__ bias,
    float* __restrict__ u, int n_groups)
{
    int g = blockIdx.x * 256 + threadIdx.x;
    if (g >= n_groups) return;
    const size_t PSZ = 2ull * 117 * 117 * 128;   // floats per partial
    const float4* p0 = (const float4*)(part + (size_t)g * 8);
    const float4* p1 = (const float4*)(part + PSZ + (size_t)g * 8);
    const float4* p2 = (const float4*)(part + 2 * PSZ + (size_t)g * 8);
    const float4* bp = (const float4*)(bias + (g & 15) * 8);
    float4 a0 = p0[0], c0 = p0[1];
    float4 a1 = p1[0], c1 = p1[1];
    float4 a2 = p2[0], c2 = p2[1];
    float4 ba = bp[0], bc = bp[1];
    float x[8];
    x[0] = a0.x + a1.x + a2.x + ba.x;
    x[1] = a0.y + a1.y + a2.y + ba.y;
    x[2] = a0.z + a1.z + a2.z + ba.z;
    x[3] = a0.w + a1.w + a2.w + ba.w;
    x[4] = c0.x + c1.x + c2.x + bc.x;
    x[5] = c0.y + c1.y + c2.y + bc.y;
    x[6] = c0.z + c1.z + c2.z + bc.z;
    x[7] = c0.w + c1.w + c2.w + bc.w;
    float sq = 0.f;
#pragma unroll
    for (int j = 0; j < 8; ++j) sq += x[j] * x[j];
    float scale = (sq / (1.f + sq)) * rsqrtf(sq + 1e-7f);
    float4* d = (float4*)(u + (size_t)g * 8);
    d[0] = make_float4(x[0] * scale, x[1] * scale, x[2] * scale, x[3] * scale);
    d[1] = make_float4(x[4] * scale, x[5] * scale, x[6] * scale, x[7] * scale);
}

// ---------------- u_hat[b,j,i,o] = sum_d W[j,i,o,d] * u[b,i,d]
__global__ __launch_bounds__(256) void uhat_kernel(
    const float* __restrict__ W, const float* __restrict__ u,
    float* __restrict__ uhat)
{
    int idx = blockIdx.x * 256 + threadIdx.x;   // idx = j*N + i
    if (idx >= J_CAPS * N_CAPS) return;
    int j = idx / N_CAPS;
    int i = idx - j * N_CAPS;

    const float4* wp = (const float4*)(W + (size_t)idx * 64);
    const float4* u0 = (const float4*)(u + (size_t)i * 8);
    const float4* u1 = (const float4*)(u + ((size_t)N_CAPS + i) * 8);
    float4 u0a = u0[0], u0b = u0[1];
    float4 u1a = u1[0], u1b = u1[1];

    float o0[8], o1[8];
#pragma unroll
    for (int o = 0; o < 8; ++o) {
        float4 wa = wp[2 * o], wb = wp[2 * o + 1];
        o0[o] = wa.x * u0a.x + wa.y * u0a.y + wa.z * u0a.z + wa.w * u0a.w
              + wb.x * u0b.x + wb.y * u0b.y + wb.z * u0b.z + wb.w * u0b.w;
        o1[o] = wa.x * u1a.x + wa.y * u1a.y + wa.z * u1a.z + wa.w * u1a.w
              + wb.x * u1b.x + wb.y * u1b.y + wb.z * u1b.z + wb.w * u1b.w;
    }
    float4* d0 = (float4*)(uhat + ((size_t)(0 * J_CAPS + j) * N_CAPS + i) * 8);
    float4* d1 = (float4*)(uhat + ((size_t)(1 * J_CAPS + j) * N_CAPS + i) * 8);
    d0[0] = make_float4(o0[0], o0[1], o0[2], o0[3]);
    d0[1] = make_float4(o0[4], o0[5], o0[6], o0[7]);
    d1[0] = make_float4(o1[0], o1[1], o1[2], o1[3]);
    d1[1] = make_float4(o1[4], o1[5], o1[6], o1[7]);
}

// ---------------- fused routing iteration (MODE 0/1/2)
template <int MODE>
__global__ __launch_bounds__(256) void routing_kernel(
    const float* __restrict__ uhat, const float* __restrict__ vprev,
    const float* __restrict__ b_in, float* __restrict__ b_out,
    float* __restrict__ s)
{
    const int bb = blockIdx.y;
    __shared__ float vsh[64];
    __shared__ float ssh[64];
    if (threadIdx.x < 64) {
        ssh[threadIdx.x] = 0.f;
        vsh[threadIdx.x] = (MODE > 0) ? vprev[bb * 64 + threadIdx.x] : 0.f;
    }
    __syncthreads();

    float acc[64];
#pragma unroll
    for (int k = 0; k < 64; ++k) acc[k] = 0.f;

    const float* ub = uhat + (size_t)bb * J_CAPS * (size_t)N_CAPS * 8;
    for (int i = blockIdx.x * 256 + threadIdx.x; i < N_CAPS; i += gridDim.x * 256) {
        float uh[64];
#pragma unroll
        for (int j = 0; j < 8; ++j) {
            const float* p = ub + ((size_t)j * N_CAPS + i) * 8;
            float4 x0 = *(const float4*)p;
            float4 x1 = *(const float4*)(p + 4);
            uh[j * 8 + 0] = x0.x; uh[j * 8 + 1] = x0.y;
            uh[j * 8 + 2] = x0.z; uh[j * 8 + 3] = x0.w;
            uh[j * 8 + 4] = x1.x; uh[j * 8 + 5] = x1.y;
            uh[j * 8 + 6] = x1.z; uh[j * 8 + 7] = x1.w;
        }
        float c[8];
        if (MODE == 0) {
#pragma unroll
            for (int j = 0; j < 8; ++j) c[j] = 0.125f;
        } else {
            float bj[8];
#pragma unroll
            for (int j = 0; j < 8; ++j) {
                float d = 0.f;
#pragma unroll
                for (int o = 0; o < 8; ++o) d += vsh[j * 8 + o] * uh[j * 8 + o];
                bj[j] = d;
            }
            if (MODE == 2) {
#pragma unroll
                for (int j = 0; j < 8; ++j)
                    bj[j] += b_in[((size_t)bb * 8 + j) * N_CAPS + i];
            } else {
#pragma unroll
                for (int j = 0; j < 8; ++j)
                    b_out[((size_t)bb * 8 + j) * N_CAPS + i] = bj[j];
            }
            float m = bj[0];
#pragma unroll
            for (int j = 1; j < 8; ++j) m = fmaxf(m, bj[j]);
            float se = 0.f;
#pragma unroll
            for (int j = 0; j < 8; ++j) { c[j] = __expf(bj[j] - m); se += c[j]; }
            float inv = 1.f / se;
#pragma unroll
            for (int j = 0; j < 8; ++j) c[j] *= inv;
        }
#pragma unroll
        for (int k = 0; k < 64; ++k) acc[k] += c[k >> 3] * uh[k];
    }

#pragma unroll
    for (int k = 0; k < 64; ++k) {
        float v = acc[k];
        for (int off = 32; off > 0; off >>= 1)
            v += __shfl_down(v, off, 64);
        if ((threadIdx.x & 63) == 0) atomicAdd(&ssh[k], v);
    }
    __syncthreads();
    if (threadIdx.x < 64) atomicAdd(&s[bb * 64 + threadIdx.x], ssh[threadIdx.x]);
}

// ---------------- squash of s -> v
__global__ void squash_v_kernel(const float* __restrict__ s, float* __restrict__ v)
{
    int t = threadIdx.x;
    if (t >= 16) return;
    const float4* p = (const float4*)(s + t * 8);
    float4 a = p[0], c = p[1];
    float sq = a.x * a.x + a.y * a.y + a.z * a.z + a.w * a.w
             + c.x * c.x + c.y * c.y + c.z * c.z + c.w * c.w;
    float scale = (sq / (1.f + sq)) * rsqrtf(sq + 1e-7f);
    float4* d = (float4*)(v + t * 8);
    d[0] = make_float4(a.x * scale, a.y * scale, a.z * scale, a.w * scale);
    d[1] = make_float4(c.x * scale, c.y * scale, c.z * scale, c.w * scale);
}

__global__ void zero_kernel(float* p, int n)
{
    int i = blockIdx.x * 256 + threadIdx.x;
    if (i < n) p[i] = 0.f;
}

extern "C" void kernel_launch(void* const* d_in, const int* in_sizes, int n_in,
                              void* d_out, int out_size, void* d_ws, size_t ws_size,
                              hipStream_t stream)
{
    const float* in = (const float*)d_in[0];
    const float* w1 = (const float*)d_in[1];
    const float* b1 = (const float*)d_in[2];
    const float* w2 = (const float*)d_in[3];
    const float* b2 = (const float*)d_in[4];
    const float* Wc = (const float*)d_in[5];
    float* out = (float*)d_out;
    char* wsb  = (char*)d_ws;

    // workspace layout (bytes):
    //  [0, 112,140,288):  uhat fp32 [2,8,219024,8]; earlier in the stream this
    //                     region is aliased by:
    //                       x1bf bf16 [2,242,242,256]      = [0, 59,969,536)
    //                       pcpart fp32 [3][2,117,117,128] = [59,969,536, 102,022,144)
    //                     (both dead before uhat is written)
    //  [112,140,288):     pc/u fp32 (14,017,536 B)
    //  [126,157,824):     blog fp32 (14,017,536 B)
    //  [140,175,360):     w2t bf16 (5,308,416 B)
    //  [145,483,776):     sbuf (512 B); [145,484,288): vbuf (512 B)
    float*          uhat   = (float*)wsb;
    unsigned short* x1bf   = (unsigned short*)wsb;
    float*          pcpart = (float*)(wsb + 59969536);
    float*          pc     = (float*)(wsb + 112140288);
    float*          blog   = (float*)(wsb + 126157824);
    unsigned short* w2t    = (unsigned short*)(wsb + 140175360);
    float*          sbuf   = (float*)(wsb + 145483776);
    float*          vbuf   = (float*)(wsb + 145484288);

    w2_convert_kernel<<<(81 * 128 * 256 + 255) / 256, 256, 0, stream>>>(w2, w2t);
    conv1_kernel<<<dim3(16, 242, 2), 256, 0, stream>>>(in, w1, b1, x1bf);
    conv2_mfma_kernel<<<dim3(2, 117, 6), 256, 0, stream>>>(x1bf, w2t, pcpart);
    squash_u_kernel<<<(2 * N_CAPS + 255) / 256, 256, 0, stream>>>(pcpart, b2, pc, 2 * N_CAPS);
    uhat_kernel<<<(J_CAPS * N_CAPS + 255) / 256, 256, 0, stream>>>(Wc, pc, uhat);

    zero_kernel<<<1, 128, 0, stream>>>(sbuf, 128);
    routing_kernel<0><<<dim3(256, 2), 256, 0, stream>>>(uhat, nullptr, nullptr, nullptr, sbuf);
    squash_v_kernel<<<1, 64, 0, stream>>>(sbuf, vbuf);

    zero_kernel<<<1, 128, 0, stream>>>(sbuf, 128);
    routing_kernel<1><<<dim3(256, 2), 256, 0, stream>>>(uhat, vbuf, nullptr, blog, sbuf);
    squash_v_kernel<<<1, 64, 0, stream>>>(sbuf, vbuf);

    zero_kernel<<<1, 128, 0, stream>>>(sbuf, 128);
    routing_kernel<2><<<dim3(256, 2), 256, 0, stream>>>(uhat, vbuf, blog, nullptr, sbuf);
    squash_v_kernel<<<1, 64, 0, stream>>>(sbuf, out);
}